// Round 1
// baseline (1114.351 us; speedup 1.0000x reference)
//
#include <hip/hip_runtime.h>
#include <math.h>

#define TPB 512        // 8 waves: wave w owns row-tile (w + t*8)
#define E 16           // elements per block
#define VSTR 264       // [e][k] stride for vector-activation LDS buffers (f16)
#define SSTR 392       // scat stride
#define OSTR 136       // souts stride
#define SLOPE_VN 0.2f
#define SLOPE_SCA 0.01f
#define EPS_VN 1e-6f

using hfrag = __attribute__((ext_vector_type(8))) _Float16;
using h4    = __attribute__((ext_vector_type(4))) _Float16;
using ffrag = __attribute__((ext_vector_type(4))) float;

__device__ __forceinline__ ffrag mfma(hfrag a, hfrag b, ffrag c) {
  return __builtin_amdgcn_mfma_f32_16x16x32_f16(a, b, c, 0, 0, 0);
}

// ---- f16 weight pointers (into d_ws) ----
struct WB {
  const _Float16 *g1_Wvh,*g1_Ws,*g1_Wvo,*g1_Wg,*g1_Wd;
  const _Float16 *g2_Wvh,*g2_Ws,*g2_Wvo,*g2_Wg;
  const _Float16 *a1_Wvh,*a1_Ws,*a1_Wvo,*a1_Wg,*a1_Wd;
  const _Float16 *a2_Wvh,*a2_Ws,*a2_Wvo,*a2_Wg,*a2_Wd;
  const _Float16 *f_Wvh;
  const float *g1_bg,*g2_bg,*a1_bg,*a2_bg,*f_Ws;
};

// ---- weight f32->f16 conversion pre-pass ----
struct CvtJobs { const float* src[20]; _Float16* dst[20]; int n[20]; };

__global__ void cvt_kernel(CvtJobs J) {
  const int j = blockIdx.y;
  const float* __restrict__ s = J.src[j];
  _Float16* __restrict__ d = J.dst[j];
  const int n = J.n[j];
  for (int i = blockIdx.x * blockDim.x + threadIdx.x; i < n;
       i += gridDim.x * blockDim.x)
    d[i] = (_Float16)s[i];
}

// ---- GEMM helpers ----
// Vector GEMM: acc[t][c] += W[O][C] * v_c, tiles = wave + 8*t.
template<int TT, int KS>
__device__ __forceinline__ void gemmV(const _Float16* __restrict__ W, int C,
                                      const _Float16* vb, ffrag acc[TT][3]) {
  const int m = threadIdx.x & 15;
  const int q = (threadIdx.x >> 4) & 3;
  const int w = threadIdx.x >> 6;
  #pragma unroll
  for (int ks = 0; ks < KS; ++ks) {
    const int k = ks * 32 + q * 8;
    hfrag b0 = *(const hfrag*)(vb + 0 * E * VSTR + m * VSTR + k);
    hfrag b1 = *(const hfrag*)(vb + 1 * E * VSTR + m * VSTR + k);
    hfrag b2 = *(const hfrag*)(vb + 2 * E * VSTR + m * VSTR + k);
    #pragma unroll
    for (int t = 0; t < TT; ++t) {
      const int row = (w + t * 8) * 16 + m;
      hfrag a = *(const hfrag*)(W + (size_t)row * C + k);
      acc[t][0] = mfma(a, b0, acc[t][0]);
      acc[t][1] = mfma(a, b1, acc[t][1]);
      acc[t][2] = mfma(a, b2, acc[t][2]);
    }
  }
}

// Scalar GEMM: acc[t] += W[O][C] * s
template<int TT, int KS>
__device__ __forceinline__ void gemmS(const _Float16* __restrict__ W, int C,
                                      const _Float16* sb, int sstr, ffrag acc[TT]) {
  const int m = threadIdx.x & 15;
  const int q = (threadIdx.x >> 4) & 3;
  const int w = threadIdx.x >> 6;
  #pragma unroll
  for (int ks = 0; ks < KS; ++ks) {
    const int k = ks * 32 + q * 8;
    hfrag b = *(const hfrag*)(sb + m * sstr + k);
    #pragma unroll
    for (int t = 0; t < TT; ++t) {
      const int row = (w + t * 8) * 16 + m;
      hfrag a = *(const hfrag*)(W + (size_t)row * C + k);
      acc[t] = mfma(a, b, acc[t]);
    }
  }
}

// Store a C/D fragment into an [e][k] LDS buffer (4 consecutive k = rows).
__device__ __forceinline__ void stCD(_Float16* buf, int stride, int tile, ffrag v) {
  const int e = threadIdx.x & 15;
  const int q = (threadIdx.x >> 4) & 3;
  h4 p;
  p[0] = (_Float16)v[0]; p[1] = (_Float16)v[1];
  p[2] = (_Float16)v[2]; p[3] = (_Float16)v[3];
  *(h4*)(buf + e * stride + tile * 16 + q * 4) = p;
}

__device__ __forceinline__ float sigm(float x) { return 1.f / (1.f + expf(-x)); }

__global__ __launch_bounds__(TPB, 4) void pe_kernel(
    const float* __restrict__ h_sca, const float* __restrict__ h_vec,
    const float* __restrict__ pos_compose, const float* __restrict__ pos,
    WB W, const int* __restrict__ idx_focal, float* __restrict__ out, int F) {
  __shared__ _Float16 sv [3 * E * VSTR];  // current vector features, [comp][e][k]
  __shared__ _Float16 svh[3 * E * VSTR];  // vh
  __shared__ _Float16 scat[E * SSTR];     // [vnorm | s | inner] per element
  __shared__ _Float16 souts[E * OSTR];    // raw out_s
  __shared__ float srel[E * 3];

  const int t = threadIdx.x;
  const int wv = t >> 6;          // 0..7
  const int q = (t >> 4) & 3;
  const int el = t >> 5;          // gather: element handled by 32 threads
  const int c5 = t & 31;
  const int eg = blockIdx.x * E + el;

  // ======== gather (f32 -> f16 LDS, vectorized float4) ========
  {
    const int idx = (eg < F) ? idx_focal[eg] : 0;
    // h_vec row = 192 floats = 48 float4; transpose [c][comp] -> [comp][c]
    const float4* __restrict__ vsrc = (const float4*)(h_vec + (size_t)idx * 192);
    #pragma unroll
    for (int it = 0; it < 2; ++it) {
      const int j = c5 + it * 32;
      if (j < 48) {
        const float4 vv = vsrc[j];
        const int b = 4 * j;
        const float fv[4] = {vv.x, vv.y, vv.z, vv.w};
        #pragma unroll
        for (int m2 = 0; m2 < 4; ++m2) {
          const int lin = b + m2;
          sv[(lin % 3) * E * VSTR + el * VSTR + lin / 3] = (_Float16)fv[m2];
        }
      }
    }
    // h_sca row = 256 floats = 64 float4
    const float4* __restrict__ ssrc = (const float4*)(h_sca + (size_t)idx * 256);
    #pragma unroll
    for (int it = 0; it < 2; ++it) {
      const int j = c5 + it * 32;
      const float4 vv = ssrc[j];
      h4 p;
      p[0] = (_Float16)vv.x; p[1] = (_Float16)vv.y;
      p[2] = (_Float16)vv.z; p[3] = (_Float16)vv.w;
      *(h4*)(scat + el * SSTR + 128 + 4 * j) = p;
    }
    if (c5 < 3 && eg < F)
      srel[el * 3 + c5] = pos[(size_t)eg * 3 + c5] - pos_compose[(size_t)idx * 3 + c5];
  }
  __syncthreads();

  ffrag zero = {0.f, 0.f, 0.f, 0.f};

  // ================= g1: perceptron (C=64 -> H=128 -> O=128) =================
  {
    ffrag vh[1][3];
    for (int c = 0; c < 3; ++c) vh[0][c] = zero;
    gemmV<1, 2>(W.g1_Wvh, 64, sv, vh);
    {
      for (int c = 0; c < 3; ++c) stCD(svh + c * E * VSTR, VSTR, wv, vh[0][c]);
      ffrag n;
      #pragma unroll
      for (int r = 0; r < 4; ++r)
        n[r] = sqrtf(vh[0][0][r]*vh[0][0][r] + vh[0][1][r]*vh[0][1][r] + vh[0][2][r]*vh[0][2][r]);
      stCD(scat, SSTR, wv, n);   // vnorm -> scat[0:128]
    }
    __syncthreads();

    ffrag so[1]; so[0] = zero;
    gemmS<1, 12>(W.g1_Ws, 384, scat, SSTR, so);
    __syncthreads();               // all scat reads done
    {
      stCD(souts, OSTR, wv, so[0]);                   // raw out_s
      ffrag l;
      for (int r = 0; r < 4; ++r) { float x = so[0][r]; l[r] = x >= 0.f ? x : SLOPE_SCA * x; }
      stCD(scat + 128, SSTR, wv, l);                  // s for g2 at [128:256]
    }
    __syncthreads();

    ffrag ov[1][3]; ffrag g[1];
    g[0] = zero; for (int c = 0; c < 3; ++c) ov[0][c] = zero;
    gemmV<1, 4>(W.g1_Wvo, 128, svh, ov);
    gemmS<1, 4>(W.g1_Wg, 128, souts, OSTR, g);
    {
      const float4 b = *(const float4*)(W.g1_bg + wv * 16 + q * 4);
      const float bb[4] = {b.x, b.y, b.z, b.w};
      #pragma unroll
      for (int r = 0; r < 4; ++r) {
        float gg = sigm(g[0][r] + bb[r]);
        ov[0][0][r] *= gg; ov[0][1][r] *= gg; ov[0][2][r] *= gg;
      }
      for (int c = 0; c < 3; ++c) stCD(sv + c * E * VSTR, VSTR, wv, ov[0][c]);
    }
    __syncthreads();               // v_new visible

    ffrag d[1][3];
    for (int c = 0; c < 3; ++c) d[0][c] = zero;
    gemmV<1, 4>(W.g1_Wd, 128, sv, d);
    __syncthreads();               // all v_new reads done
    {
      #pragma unroll
      for (int r = 0; r < 4; ++r) {
        float x0 = ov[0][0][r], x1 = ov[0][1][r], x2 = ov[0][2][r];
        float d0 = d[0][0][r],  d1 = d[0][1][r],  d2 = d[0][2][r];
        float dot = x0*d0 + x1*d1 + x2*d2;
        float kk = dot / (d0*d0 + d1*d1 + d2*d2 + EPS_VN);
        if (dot < 0.f) {
          ov[0][0][r] = SLOPE_VN*x0 + (1.f-SLOPE_VN)*(x0 - kk*d0);
          ov[0][1][r] = SLOPE_VN*x1 + (1.f-SLOPE_VN)*(x1 - kk*d1);
          ov[0][2][r] = SLOPE_VN*x2 + (1.f-SLOPE_VN)*(x2 - kk*d2);
        }
      }
      for (int c = 0; c < 3; ++c) stCD(sv + c * E * VSTR, VSTR, wv, ov[0][c]);
    }
    __syncthreads();
  }

  // ================= g2: linear (128 -> 128) =================
  {
    ffrag vh[1][3];
    for (int c = 0; c < 3; ++c) vh[0][c] = zero;
    gemmV<1, 4>(W.g2_Wvh, 128, sv, vh);
    {
      for (int c = 0; c < 3; ++c) stCD(svh + c * E * VSTR, VSTR, wv, vh[0][c]);
      ffrag n;
      for (int r = 0; r < 4; ++r)
        n[r] = sqrtf(vh[0][0][r]*vh[0][0][r] + vh[0][1][r]*vh[0][1][r] + vh[0][2][r]*vh[0][2][r]);
      stCD(scat, SSTR, wv, n);
    }
    __syncthreads();

    ffrag so[1]; so[0] = zero;
    gemmS<1, 8>(W.g2_Ws, 256, scat, SSTR, so);
    __syncthreads();
    {
      stCD(souts, OSTR, wv, so[0]);
      stCD(scat + 256, SSTR, wv, so[0]);              // s for a1 at [256:384], no act
    }
    __syncthreads();

    ffrag ov[1][3]; ffrag g[1];
    g[0] = zero; for (int c = 0; c < 3; ++c) ov[0][c] = zero;
    gemmV<1, 4>(W.g2_Wvo, 128, svh, ov);
    gemmS<1, 4>(W.g2_Wg, 128, souts, OSTR, g);
    {
      const float4 b = *(const float4*)(W.g2_bg + wv * 16 + q * 4);
      const float bb[4] = {b.x, b.y, b.z, b.w};
      for (int r = 0; r < 4; ++r) {
        float gg = sigm(g[0][r] + bb[r]);
        ov[0][0][r] *= gg; ov[0][1][r] *= gg; ov[0][2][r] *= gg;
      }
      for (int c = 0; c < 3; ++c) stCD(sv + c * E * VSTR, VSTR, wv, ov[0][c]);
    }
    __syncthreads();
  }

  // ================= a1: perceptron (128 -> H=256 -> O=256) =================
  {
    ffrag vh[2][3];
    #pragma unroll
    for (int i = 0; i < 2; ++i) for (int c = 0; c < 3; ++c) vh[i][c] = zero;
    gemmV<2, 4>(W.a1_Wvh, 128, sv, vh);
    #pragma unroll
    for (int i = 0; i < 2; ++i) {
      const int tile = wv + i * 8;
      for (int c = 0; c < 3; ++c) stCD(svh + c * E * VSTR, VSTR, tile, vh[i][c]);
      ffrag n;
      for (int r = 0; r < 4; ++r)
        n[r] = sqrtf(vh[i][0][r]*vh[i][0][r] + vh[i][1][r]*vh[i][1][r] + vh[i][2][r]*vh[i][2][r]);
      stCD(scat, SSTR, tile, n);   // vnorm -> scat[0:256]
    }
    __syncthreads();

    ffrag so[1]; so[0] = zero;
    gemmS<1, 12>(W.a1_Ws, 384, scat, SSTR, so);
    __syncthreads();
    {
      stCD(souts, OSTR, wv, so[0]);
      ffrag l;
      for (int r = 0; r < 4; ++r) { float x = so[0][r]; l[r] = x >= 0.f ? x : SLOPE_SCA * x; }
      stCD(scat + 128, SSTR, wv, l);                  // s1 for a2 at [128:256]
    }
    __syncthreads();

    ffrag ov[2][3]; ffrag g[2];
    #pragma unroll
    for (int i = 0; i < 2; ++i) { g[i] = zero; for (int c = 0; c < 3; ++c) ov[i][c] = zero; }
    gemmV<2, 8>(W.a1_Wvo, 256, svh, ov);
    gemmS<2, 4>(W.a1_Wg, 128, souts, OSTR, g);
    #pragma unroll
    for (int i = 0; i < 2; ++i) {
      const int tile = wv + i * 8;
      const float4 b = *(const float4*)(W.a1_bg + tile * 16 + q * 4);
      const float bb[4] = {b.x, b.y, b.z, b.w};
      for (int r = 0; r < 4; ++r) {
        float gg = sigm(g[i][r] + bb[r]);
        ov[i][0][r] *= gg; ov[i][1][r] *= gg; ov[i][2][r] *= gg;
      }
      for (int c = 0; c < 3; ++c) stCD(sv + c * E * VSTR, VSTR, tile, ov[i][c]);
    }
    __syncthreads();

    ffrag d[2][3];
    #pragma unroll
    for (int i = 0; i < 2; ++i) for (int c = 0; c < 3; ++c) d[i][c] = zero;
    gemmV<2, 8>(W.a1_Wd, 256, sv, d);
    __syncthreads();
    #pragma unroll
    for (int i = 0; i < 2; ++i) {
      for (int r = 0; r < 4; ++r) {
        float x0 = ov[i][0][r], x1 = ov[i][1][r], x2 = ov[i][2][r];
        float d0 = d[i][0][r],  d1 = d[i][1][r],  d2 = d[i][2][r];
        float dot = x0*d0 + x1*d1 + x2*d2;
        float kk = dot / (d0*d0 + d1*d1 + d2*d2 + EPS_VN);
        if (dot < 0.f) {
          ov[i][0][r] = SLOPE_VN*x0 + (1.f-SLOPE_VN)*(x0 - kk*d0);
          ov[i][1][r] = SLOPE_VN*x1 + (1.f-SLOPE_VN)*(x1 - kk*d1);
          ov[i][2][r] = SLOPE_VN*x2 + (1.f-SLOPE_VN)*(x2 - kk*d2);
        }
      }
      for (int c = 0; c < 3; ++c) stCD(sv + c * E * VSTR, VSTR, wv + i * 8, ov[i][c]);
    }
    __syncthreads();
  }

  // ---- mid: inner[e][h] = <v1[128+h], relpos[e]> -> scat[256:384] ----
  {
    const float r0 = srel[el * 3 + 0], r1 = srel[el * 3 + 1], r2 = srel[el * 3 + 2];
    for (int h = c5; h < 128; h += 32) {
      float x0 = (float)sv[0 * E * VSTR + el * VSTR + 128 + h];
      float x1 = (float)sv[1 * E * VSTR + el * VSTR + 128 + h];
      float x2 = (float)sv[2 * E * VSTR + el * VSTR + 128 + h];
      scat[el * SSTR + 256 + h] = (_Float16)(x0 * r0 + x1 * r1 + x2 * r2);
    }
  }
  // no sync needed yet: a2's vh GEMM only reads sv

  // ================= a2: perceptron (v = v1[:,:128], s2 = [s1, inner]) =========
  {
    ffrag vh[1][3];
    for (int c = 0; c < 3; ++c) vh[0][c] = zero;
    gemmV<1, 4>(W.a2_Wvh, 128, sv, vh);
    {
      for (int c = 0; c < 3; ++c) stCD(svh + c * E * VSTR, VSTR, wv, vh[0][c]);
      ffrag n;
      for (int r = 0; r < 4; ++r)
        n[r] = sqrtf(vh[0][0][r]*vh[0][0][r] + vh[0][1][r]*vh[0][1][r] + vh[0][2][r]*vh[0][2][r]);
      stCD(scat, SSTR, wv, n);
    }
    __syncthreads();

    ffrag so[1]; so[0] = zero;
    gemmS<1, 12>(W.a2_Ws, 384, scat, SSTR, so);
    __syncthreads();
    {
      stCD(souts, OSTR, wv, so[0]);
      ffrag l;
      for (int r = 0; r < 4; ++r) { float x = so[0][r]; l[r] = x >= 0.f ? x : SLOPE_SCA * x; }
      stCD(scat + 128, SSTR, wv, l);                  // s_a2 for f at [128:256]
    }
    __syncthreads();

    ffrag ov[1][3]; ffrag g[1];
    g[0] = zero; for (int c = 0; c < 3; ++c) ov[0][c] = zero;
    gemmV<1, 4>(W.a2_Wvo, 128, svh, ov);
    gemmS<1, 4>(W.a2_Wg, 128, souts, OSTR, g);
    {
      const float4 b = *(const float4*)(W.a2_bg + wv * 16 + q * 4);
      const float bb[4] = {b.x, b.y, b.z, b.w};
      for (int r = 0; r < 4; ++r) {
        float gg = sigm(g[0][r] + bb[r]);
        ov[0][0][r] *= gg; ov[0][1][r] *= gg; ov[0][2][r] *= gg;
      }
      for (int c = 0; c < 3; ++c) stCD(sv + c * E * VSTR, VSTR, wv, ov[0][c]);
    }
    __syncthreads();

    ffrag d[1][3];
    for (int c = 0; c < 3; ++c) d[0][c] = zero;
    gemmV<1, 4>(W.a2_Wd, 128, sv, d);
    __syncthreads();
    {
      for (int r = 0; r < 4; ++r) {
        float x0 = ov[0][0][r], x1 = ov[0][1][r], x2 = ov[0][2][r];
        float d0 = d[0][0][r],  d1 = d[0][1][r],  d2 = d[0][2][r];
        float dot = x0*d0 + x1*d1 + x2*d2;
        float kk = dot / (d0*d0 + d1*d1 + d2*d2 + EPS_VN);
        if (dot < 0.f) {
          ov[0][0][r] = SLOPE_VN*x0 + (1.f-SLOPE_VN)*(x0 - kk*d0);
          ov[0][1][r] = SLOPE_VN*x1 + (1.f-SLOPE_VN)*(x1 - kk*d1);
          ov[0][2][r] = SLOPE_VN*x2 + (1.f-SLOPE_VN)*(x2 - kk*d2);
        }
      }
      for (int c = 0; c < 3; ++c) stCD(sv + c * E * VSTR, VSTR, wv, ov[0][c]);
    }
    __syncthreads();
  }

  // ================= f: vnorm + final dot =================
  {
    ffrag vh[1][3];
    for (int c = 0; c < 3; ++c) vh[0][c] = zero;
    gemmV<1, 4>(W.f_Wvh, 128, sv, vh);
    {
      ffrag n;
      for (int r = 0; r < 4; ++r)
        n[r] = sqrtf(vh[0][0][r]*vh[0][0][r] + vh[0][1][r]*vh[0][1][r] + vh[0][2][r]*vh[0][2][r]);
      stCD(scat, SSTR, wv, n);
    }
    __syncthreads();

    float part = 0.f;
    for (int c = c5; c < 256; c += 32)
      part += (float)scat[el * SSTR + c] * W.f_Ws[c];
    part += __shfl_xor(part, 16, 32);
    part += __shfl_xor(part, 8, 32);
    part += __shfl_xor(part, 4, 32);
    part += __shfl_xor(part, 2, 32);
    part += __shfl_xor(part, 1, 32);
    if (c5 == 0 && eg < F) out[eg] = part;
  }
}

extern "C" void kernel_launch(void* const* d_in, const int* in_sizes, int n_in,
                              void* d_out, int out_size, void* d_ws, size_t ws_size,
                              hipStream_t stream) {
  const float* h_sca       = (const float*)d_in[0];
  const float* h_vec       = (const float*)d_in[1];
  const float* pos_compose = (const float*)d_in[2];
  const float* pos         = (const float*)d_in[3];
  const int* idx_focal     = (const int*)d_in[29];
  const int F = in_sizes[29];

  // weight conversion jobs: d_in index -> packed f16 in d_ws
  const int widx[20] = {4,5,6,7,9, 10,11,12,13, 15,16,17,18,20, 21,22,23,24,26, 27};
  CvtJobs J;
  _Float16* wsp = (_Float16*)d_ws;
  size_t off = 0;
  const _Float16* wptr[20];
  for (int j = 0; j < 20; ++j) {
    J.src[j] = (const float*)d_in[widx[j]];
    J.dst[j] = wsp + off;
    J.n[j]   = in_sizes[widx[j]];
    wptr[j]  = wsp + off;
    off += in_sizes[widx[j]];
  }
  cvt_kernel<<<dim3(32, 20), dim3(256), 0, stream>>>(J);

  WB W;
  W.g1_Wvh = wptr[0];  W.g1_Ws = wptr[1];  W.g1_Wvo = wptr[2];  W.g1_Wg = wptr[3];  W.g1_Wd = wptr[4];
  W.g2_Wvh = wptr[5];  W.g2_Ws = wptr[6];  W.g2_Wvo = wptr[7];  W.g2_Wg = wptr[8];
  W.a1_Wvh = wptr[9];  W.a1_Ws = wptr[10]; W.a1_Wvo = wptr[11]; W.a1_Wg = wptr[12]; W.a1_Wd = wptr[13];
  W.a2_Wvh = wptr[14]; W.a2_Ws = wptr[15]; W.a2_Wvo = wptr[16]; W.a2_Wg = wptr[17]; W.a2_Wd = wptr[18];
  W.f_Wvh  = wptr[19];
  W.g1_bg = (const float*)d_in[8];
  W.g2_bg = (const float*)d_in[14];
  W.a1_bg = (const float*)d_in[19];
  W.a2_bg = (const float*)d_in[25];
  W.f_Ws  = (const float*)d_in[28];

  const int blocks = (F + E - 1) / E;
  pe_kernel<<<dim3(blocks), dim3(TPB), 0, stream>>>(
      h_sca, h_vec, pos_compose, pos, W, idx_focal, (float*)d_out, F);
}